// Round 7
// baseline (43.666 us; speedup 1.0000x reference)
//
#include <hip/hip_runtime.h>

namespace {

using v2f = __attribute__((ext_vector_type(2))) float;

constexpr int NQ      = 14;
constexpr int NSTATES = 1 << NQ;
constexpr int BLOCK   = 1024;
constexpr int NWAVES  = BLOCK / 64;

// ---------------- compile-time GF(2) machinery ----------------
constexpr unsigned cparity(unsigned x){ x^=x>>8; x^=x>>4; x^=x>>2; x^=x>>1; return x&1u; }

struct Mat { unsigned row[NQ]; unsigned col[NQ]; };

constexpr Mat m_after(int nr){
  Mat m{};
  for(int p=0;p<NQ;++p){ m.row[p]=1u<<p; m.col[p]=1u<<p; }
  for(int l=0;l<nr;++l)
    for(int q=0;q<NQ;++q){
      int cq=(q==NQ-1)?NQ-1:q, tq=(q==NQ-1)?0:q+1;
      int Pc=NQ-1-cq, Pt=NQ-1-tq;
      m.row[Pt]^=m.row[Pc]; m.col[Pc]^=m.col[Pt];
    }
  return m;
}

constexpr Mat M1=m_after(1), M2=m_after(2), M3=m_after(3);
constexpr unsigned amask(int q){ return M1.col[NQ-1-q]; }
constexpr unsigned arow (int q){ return M1.row[NQ-1-q]; }
constexpr unsigned bmask(int q){ return M2.col[NQ-1-q]; }
constexpr unsigned brow (int q){ return M2.row[NQ-1-q]; }

constexpr int rank_of(const unsigned* v, int n){
  unsigned a[24]{};
  for(int i=0;i<n;++i) a[i]=v[i];
  int r=0;
  for(int bit=15;bit>=0;--bit){
    int p=-1;
    for(int i=r;i<n;++i){ if((a[i]>>bit)&1){ p=i; break; } }
    if(p<0) continue;
    unsigned t=a[r]; a[r]=a[p]; a[p]=t;
    for(int i=0;i<n;++i) if(i!=r && ((a[i]>>bit)&1)) a[i]^=a[r];
    ++r;
  }
  return r;
}

struct Plan {
  unsigned A[14], B[14], C[14];
  int BlaneGi[6]; unsigned BlanePi4[6];
  int BregGi[4];  unsigned BregEps[4];
  int CregGi[4];  unsigned CregEps[4];
  int ClaneGi[4]; unsigned ClaneEps[4];
  unsigned EJ4[14], ET[14];
};

constexpr Plan make_plan(){
  Plan P{};
  for(int t=0;t<14;++t) P.A[t]=amask(t);
  for(int t=0;t<4;++t){ P.B[t]=amask(10+t); P.BregGi[t]=10+t; }
  bool used[14]{}; int picked[14]{}; int np=0;
  {
    unsigned cur[20]{}; int nc=0;
    for(int t=0;t<4;++t) cur[nc++]=P.B[t];
    for(int q=0;q<14 && np<10;++q){
      cur[nc]=bmask(q);
      if(rank_of(cur,nc+1)==nc+1){ ++nc; picked[np++]=q; used[q]=true; }
    }
  }
  for(int i=0;i<6;++i){ P.B[4+i]=bmask(picked[i]); P.BlaneGi[i]=14+picked[i]; }
  int wq[4]{}, un[4]{}; int nu=0;
  for(int i=0;i<4;++i){ wq[i]=picked[6+i]; P.B[10+i]=bmask(wq[i]); P.CregGi[i]=14+wq[i]; }
  for(int q=0;q<14;++q) if(!used[q]) un[nu++]=q;
  for(int i=0;i<4;++i) P.ClaneGi[i]=14+un[i];
  for(int i=0;i<4;++i){ unsigned m=0;
    for(int t=0;t<10;++t) m |= cparity(arow(10+i)&P.B[4+t])<<t;
    P.BregEps[i]=m; }
  for(int i=0;i<6;++i){ unsigned m=0;
    for(int t=0;t<4;++t) m |= cparity(brow(picked[i])&P.B[t])<<t;
    P.BlanePi4[i]=m; }
  for(int t=0;t<4;++t) P.C[t]=bmask(wq[t]);
  for(int t=0;t<4;++t) P.C[4+t]=bmask(un[t]);
  {
    unsigned cc[20]{}; int n=0;
    for(int t=0;t<8;++t) cc[n++]=P.C[t];
    int pos=8;
    for(int p=0;p<14 && pos<14;++p){
      cc[n]=1u<<p;
      if(rank_of(cc,n+1)==n+1){ P.C[pos]=1u<<p; ++n; ++pos; }
    }
  }
  for(int i=0;i<4;++i){ unsigned m=0;
    for(int t=0;t<10;++t) m |= cparity(brow(wq[i])&P.C[4+t])<<t;
    P.CregEps[i]=m; }
  for(int i=0;i<4;++i){ unsigned m=0;
    for(int t=0;t<10;++t){ if(t==i) continue; m |= cparity(brow(un[i])&P.C[4+t])<<t; }
    P.ClaneEps[i]=m; }
  for(int w=0;w<14;++w){
    unsigned R=M3.row[NQ-1-w]; unsigned mj=0, mt=0;
    for(int t=0;t<4;++t)  mj |= cparity(R&P.C[t])<<t;
    for(int t=0;t<10;++t) mt |= cparity(R&P.C[4+t])<<t;
    P.EJ4[w]=mj; P.ET[w]=mt;
  }
  return P;
}

constexpr Plan PL = make_plan();
static_assert(rank_of(PL.A,14)==14, "phase A map not bijective");
static_assert(rank_of(PL.B,14)==14, "phase B map not bijective");
static_assert(rank_of(PL.C,14)==14, "phase C map not bijective");

// ---- basis inversion + phase transition matrices (all constexpr) ----
struct Inv { unsigned col[NQ]; };   // col[p] = coords of e_p in the basis
constexpr Inv inv_basis(const unsigned* bas){
  unsigned vec[NQ]{}, cmb[NQ]{}; bool used[NQ]{}; int pivk[NQ]{};
  for(int k=0;k<NQ;++k){ vec[k]=bas[k]; cmb[k]=1u<<k; }
  for(int b=0;b<NQ;++b){
    int p=-1;
    for(int k=0;k<NQ;++k) if(!used[k] && ((vec[k]>>b)&1)){ p=k; break; }
    used[p]=true; pivk[b]=p;
    for(int k=0;k<NQ;++k) if(k!=p && ((vec[k]>>b)&1)){ vec[k]^=vec[p]; cmb[k]^=cmb[p]; }
  }
  Inv R{};
  for(int b=0;b<NQ;++b) R.col[b]=cmb[pivk[b]];
  return R;
}
constexpr bool check_inv(const unsigned* bas, const Inv& iv){
  for(int p=0;p<NQ;++p){
    unsigned s=0;
    for(int k=0;k<NQ;++k) if((iv.col[p]>>k)&1) s^=bas[k];
    if(s != (1u<<p)) return false;
  }
  return true;
}
constexpr Inv IA = inv_basis(PL.A), IB = inv_basis(PL.B), IC = inv_basis(PL.C);
static_assert(check_inv(PL.A, IA), "IA");
static_assert(check_inv(PL.B, IB), "IB");
static_assert(check_inv(PL.C, IC), "IC");

struct Trans { unsigned t[NQ]; };   // t[k] = next-phase coords of current basis vec k
constexpr Trans trans_phys(const Inv& iv){
  Trans T{};
  for(int p=0;p<NQ;++p) T.t[p]=iv.col[p];
  return T;
}
constexpr Trans trans_of(const unsigned* cur, const Inv& iv){
  Trans T{};
  for(int k=0;k<NQ;++k){
    unsigned c=0;
    for(int p=0;p<NQ;++p) if((cur[k]>>p)&1) c^=iv.col[p];
    T.t[k]=c;
  }
  return T;
}
constexpr Trans T_PA = trans_phys(IA);
constexpr Trans T_AB = trans_of(PL.A, IB);
constexpr Trans T_BC = trans_of(PL.B, IC);

struct CJ { unsigned v[16]; };
constexpr CJ mk_cj(const Trans& T){
  CJ c{};
  for(int j=0;j<16;++j){
    unsigned s=0;
    for(int b=0;b<4;++b) if((j>>b)&1) s^=T.t[b];
    c.v[j]=s;
  }
  return c;
}
constexpr CJ CJ_PA=mk_cj(T_PA), CJ_AB=mk_cj(T_AB), CJ_BC=mk_cj(T_BC);

// ---------------- packed-f32 complex helpers ----------------
__device__ __forceinline__ v2f mkv(float a, float b){ v2f r; r[0]=a; r[1]=b; return r; }

__device__ __forceinline__ v2f pk_mul(v2f a, v2f b){
  v2f d; asm("v_pk_mul_f32 %0, %1, %2 op_sel:[0,0] op_sel_hi:[1,1]" : "=v"(d) : "v"(a), "v"(b)); return d;
}
__device__ __forceinline__ v2f pk_fma(v2f a, v2f b, v2f c){
  v2f d; asm("v_pk_fma_f32 %0, %1, %2, %3 op_sel:[0,0,0] op_sel_hi:[1,1,1]" : "=v"(d) : "v"(a), "v"(b), "v"(c)); return d;
}
__device__ __forceinline__ v2f pk_fma_swap1(v2f a, v2f b, v2f c){
  v2f d; asm("v_pk_fma_f32 %0, %1, %2, %3 op_sel:[0,1,0] op_sel_hi:[1,0,1]" : "=v"(d) : "v"(a), "v"(b), "v"(c)); return d;
}
__device__ __forceinline__ v2f cmul_pk(v2f uxx, v2f uyn, v2f s){ return pk_fma_swap1(uyn, s, pk_mul(uxx, s)); }
__device__ __forceinline__ v2f cfma_pk(v2f uxx, v2f uyn, v2f s, v2f acc){ return pk_fma_swap1(uyn, s, pk_fma(uxx, s, acc)); }

__device__ __forceinline__ float2 cmulf(float2 a, float2 b){
  return make_float2(a.x*b.x - a.y*b.y, a.x*b.y + a.y*b.x);
}
__device__ __forceinline__ v2f sel2(bool c, v2f x, v2f y){ v2f r; r[0]=c?x[0]:y[0]; r[1]=c?x[1]:y[1]; return r; }

struct GC { v2f u00x,u00n,u01x,u01n,u10x,u10n,u11x,u11n; };
__device__ __forceinline__ GC load_gc(const v2f* __restrict__ g){
  GC c{g[0],g[1],g[2],g[3],g[4],g[5],g[6],g[7]}; return c;
}

// ---- lane exchange (partner value) ----
template<int CTRL>
__device__ __forceinline__ int dpp(int x){
  return __builtin_amdgcn_update_dpp(0, x, CTRL, 0xF, 0xF, true);
}
// ^32 partner via permlane32_swap: with D=S=x, r[0]={x_lo,x_lo}, r[1]={x_hi,x_hi}
// (new_vdst gathers low halves). Partner: lane<32 -> x_hi -> r[1]; lane>=32 -> x_lo -> r[0].
__device__ __forceinline__ int x32(int x, unsigned lane){
  auto r = __builtin_amdgcn_permlane32_swap((unsigned)x, (unsigned)x, false, false);
  return (lane & 32u) ? (int)r[0] : (int)r[1];
}
// K: 0:^1 1:^2 2:^4 3:^8 4:^16 5:^32
template<int K>
__device__ __forceinline__ v2f xpart(v2f v, unsigned lane){
  int x0=__float_as_int(v[0]), x1=__float_as_int(v[1]);
  int y0, y1;
  if constexpr (K==0){ y0=dpp<0xB1>(x0);  y1=dpp<0xB1>(x1); }          // quad_perm ^1
  else if constexpr (K==1){ y0=dpp<0x4E>(x0);  y1=dpp<0x4E>(x1); }     // quad_perm ^2
  else if constexpr (K==2){                                            // ^4 (verified R4)
    y0=__builtin_amdgcn_ds_swizzle(x0,0x101F);
    y1=__builtin_amdgcn_ds_swizzle(x1,0x101F);
  }
  else if constexpr (K==3){ y0=dpp<0x128>(x0); y1=dpp<0x128>(x1); }    // row_ror:8 == ^8 (direction-free)
  else if constexpr (K==4){                                            // ^16 (verified R4)
    y0=__builtin_amdgcn_ds_swizzle(x0,0x401F);
    y1=__builtin_amdgcn_ds_swizzle(x1,0x401F);
  }
  else { y0=x32(x0,lane); y1=x32(x1,lane); }                           // ^32
  v2f r; r[0]=__int_as_float(y0); r[1]=__int_as_float(y1); return r;
}

template<int BIT>
__device__ __forceinline__ void reg_gate(v2f (&a)[16], const GC& c, bool eps){
  v2f m00x=sel2(eps,c.u11x,c.u00x), m00n=sel2(eps,c.u11n,c.u00n);
  v2f m01x=sel2(eps,c.u10x,c.u01x), m01n=sel2(eps,c.u10n,c.u01n);
  v2f m10x=sel2(eps,c.u01x,c.u10x), m10n=sel2(eps,c.u01n,c.u10n);
  v2f m11x=sel2(eps,c.u00x,c.u11x), m11n=sel2(eps,c.u00n,c.u11n);
#pragma unroll
  for(int v=0; v<16; ++v){
    if(!((v>>BIT)&1)){
      int w = v | (1<<BIT);
      v2f a0=a[v], a1=a[w];
      a[v] = cfma_pk(m01x,m01n,a1, cmul_pk(m00x,m00n,a0));
      a[w] = cfma_pk(m11x,m11n,a1, cmul_pk(m10x,m10n,a0));
    }
  }
}

template<int XK, unsigned PI4>
__device__ __forceinline__ void lane_gate(v2f (&a)[16], const GC& c, bool sel, unsigned lane){
  v2f kax0=sel2(sel,c.u11x,c.u00x), kan0=sel2(sel,c.u11n,c.u00n);
  v2f kbx0=sel2(sel,c.u10x,c.u01x), kbn0=sel2(sel,c.u10n,c.u01n);
  v2f kax1=sel2(sel,c.u00x,c.u11x), kan1=sel2(sel,c.u00n,c.u11n);
  v2f kbx1=sel2(sel,c.u01x,c.u10x), kbn1=sel2(sel,c.u01n,c.u10n);
#pragma unroll
  for(int j=0;j<16;++j){
    v2f th = xpart<XK>(a[j], lane);
    bool pi = (__builtin_popcount(PI4 & (unsigned)j) & 1) != 0;   // folds per unrolled j
    v2f kax = pi?kax1:kax0, kan = pi?kan1:kan0;
    v2f kbx = pi?kbx1:kbx0, kbn = pi?kbn1:kbn0;
    a[j] = cfma_pk(kbx,kbn,th, cmul_pk(kax,kan,a[j]));
  }
}

__device__ __forceinline__ unsigned nb_of(unsigned tid, const unsigned (&t)[NQ]){
  unsigned s=0;
#pragma unroll
  for(int k=0;k<10;++k) s ^= t[4+k] & (0u-((tid>>k)&1u));
  return s;
}

__device__ __forceinline__ void scatter16(v2f* __restrict__ st, const v2f (&a)[16],
                                          unsigned nb, const CJ& cj){
#pragma unroll
  for(int j=0;j<16;++j){
    unsigned d = nb ^ cj.v[j];
    st[d + (d>>4)] = a[j];
  }
}

// ---------------- kernels ----------------
__global__ void prep_gates(const float* __restrict__ prm, float* __restrict__ wsf){
  int t = threadIdx.x;
  if(t >= 2*NQ) return;
  int l = 1 + t/NQ, q = t % NQ;
  float ax=prm[(l*NQ+q)*3+0], ay=prm[(l*NQ+q)*3+1], az=prm[(l*NQ+q)*3+2];
  float cx,sx,cy,sy,cz,sz;
  sincosf(0.5f*ax,&sx,&cx); sincosf(0.5f*ay,&sy,&cy); sincosf(0.5f*az,&sz,&cz);
  float2 M00=make_float2(cy*cx, sy*sx),  M01=make_float2(-sy*cx,-cy*sx);
  float2 M10=make_float2(sy*cx,-cy*sx),  M11=make_float2(cy*cx,-sy*sx);
  float2 ez =make_float2(cz,-sz), ezc=make_float2(cz,sz);
  float2 U00=cmulf(ez,M00), U01=cmulf(ez,M01), U10=cmulf(ezc,M10), U11=cmulf(ezc,M11);
  float* o = wsf + t*16;
  o[0]=U00.x; o[1]=U00.x; o[2]=-U00.y; o[3]=U00.y;
  o[4]=U01.x; o[5]=U01.x; o[6]=-U01.y; o[7]=U01.y;
  o[8]=U10.x; o[9]=U10.x; o[10]=-U10.y; o[11]=U10.y;
  o[12]=U11.x; o[13]=U11.x; o[14]=-U11.y; o[15]=U11.y;
}

__global__ __launch_bounds__(BLOCK, 4) void qsim_kernel(
    const float* __restrict__ x,
    const float* __restrict__ prm,
    const float* __restrict__ gw,
    float* __restrict__ out)
{
  __shared__ v2f    st[BLOCK*17];     // phase-ordered state, 8B pad per thread (136 KiB)
  __shared__ v2f    Utab[28*8];       // gate constants
  __shared__ float2 l0c[NQ][2];
  __shared__ float  red[NWAVES][NQ];

  const int b = blockIdx.x;
  const unsigned tid = threadIdx.x;
  const unsigned lane = tid & 63u;

  // gate table -> LDS
  if(tid < 28*16) ((float*)Utab)[tid] = gw[tid];
  // layer-0 columns (x-dependent)
  if(tid < NQ){
    int q = tid;
    float ax = prm[q*3+0] + x[b*NQ+q];
    float ay = prm[q*3+1], az = prm[q*3+2];
    float cx,sx,cy,sy,cz,sz;
    sincosf(0.5f*ax,&sx,&cx); sincosf(0.5f*ay,&sy,&cy); sincosf(0.5f*az,&sz,&cz);
    l0c[q][0] = cmulf(make_float2(cz,-sz), make_float2(cy*cx,  sy*sx));   // U00
    l0c[q][1] = cmulf(make_float2(cz, sz), make_float2(sy*cx, -cy*sx));   // U10
  }
  __syncthreads();

  // ---- init: product state for s = (tid<<4)|j, scattered into phase-A layout ----
  {
    float2 Pk = l0c[0][(tid>>9)&1];
#pragma unroll
    for(int q=1;q<10;++q) Pk = cmulf(Pk, l0c[q][(tid>>(9-q))&1]);
    float2 t2[2], t4[4];
    t2[0]=cmulf(Pk,l0c[10][0]); t2[1]=cmulf(Pk,l0c[10][1]);
#pragma unroll
    for(int i=0;i<2;++i){ t4[2*i]=cmulf(t2[i],l0c[11][0]); t4[2*i+1]=cmulf(t2[i],l0c[11][1]); }
    v2f a[16];
#pragma unroll
    for(int j=0;j<16;++j){
      float2 v = cmulf(cmulf(t4[j>>2], l0c[12][(j>>1)&1]), l0c[13][j&1]);
      a[j] = mkv(v.x, v.y);
    }
    scatter16(st, a, nb_of(tid, T_PA.t), CJ_PA);
  }
  __syncthreads();

  // ---- phase A: 4 reg + 6 lane layer-1 gates ----
  {
    v2f a[16];
    const int rb = (int)tid*17;
#pragma unroll
    for(int j=0;j<16;++j) a[j] = st[rb + j];
    reg_gate<0>(a, load_gc(Utab+0*8), false);
    reg_gate<1>(a, load_gc(Utab+1*8), false);
    reg_gate<2>(a, load_gc(Utab+2*8), false);
    reg_gate<3>(a, load_gc(Utab+3*8), false);
    lane_gate<0,0u>(a, load_gc(Utab+4*8), (tid&1)!=0,  lane);
    lane_gate<1,0u>(a, load_gc(Utab+5*8), (tid&2)!=0,  lane);
    lane_gate<2,0u>(a, load_gc(Utab+6*8), (tid&4)!=0,  lane);
    lane_gate<3,0u>(a, load_gc(Utab+7*8), (tid&8)!=0,  lane);
    lane_gate<4,0u>(a, load_gc(Utab+8*8), (tid&16)!=0, lane);
    lane_gate<5,0u>(a, load_gc(Utab+9*8), (tid&32)!=0, lane);
    __syncthreads();                      // all reads done before cross-layout writes
    scatter16(st, a, nb_of(tid, T_AB.t), CJ_AB);
  }
  __syncthreads();

  // ---- phase B: 4 leftover layer-1 reg gates (runtime eps) + 6 layer-2 lane gates ----
  {
    v2f a[16];
    const int rb = (int)tid*17;
#pragma unroll
    for(int j=0;j<16;++j) a[j] = st[rb + j];
    reg_gate<0>(a, load_gc(Utab+PL.BregGi[0]*8), (__builtin_popcount(PL.BregEps[0]&tid)&1)!=0);
    reg_gate<1>(a, load_gc(Utab+PL.BregGi[1]*8), (__builtin_popcount(PL.BregEps[1]&tid)&1)!=0);
    reg_gate<2>(a, load_gc(Utab+PL.BregGi[2]*8), (__builtin_popcount(PL.BregEps[2]&tid)&1)!=0);
    reg_gate<3>(a, load_gc(Utab+PL.BregGi[3]*8), (__builtin_popcount(PL.BregEps[3]&tid)&1)!=0);
    lane_gate<0,PL.BlanePi4[0]>(a, load_gc(Utab+PL.BlaneGi[0]*8), (tid&1)!=0,  lane);
    lane_gate<1,PL.BlanePi4[1]>(a, load_gc(Utab+PL.BlaneGi[1]*8), (tid&2)!=0,  lane);
    lane_gate<2,PL.BlanePi4[2]>(a, load_gc(Utab+PL.BlaneGi[2]*8), (tid&4)!=0,  lane);
    lane_gate<3,PL.BlanePi4[3]>(a, load_gc(Utab+PL.BlaneGi[3]*8), (tid&8)!=0,  lane);
    lane_gate<4,PL.BlanePi4[4]>(a, load_gc(Utab+PL.BlaneGi[4]*8), (tid&16)!=0, lane);
    lane_gate<5,PL.BlanePi4[5]>(a, load_gc(Utab+PL.BlaneGi[5]*8), (tid&32)!=0, lane);
    __syncthreads();
    scatter16(st, a, nb_of(tid, T_BC.t), CJ_BC);
  }
  __syncthreads();

  // ---- phase C: last 8 layer-2 gates, expectation from registers ----
  {
    v2f a[16];
    const int rb = (int)tid*17;
#pragma unroll
    for(int j=0;j<16;++j) a[j] = st[rb + j];
    reg_gate<0>(a, load_gc(Utab+PL.CregGi[0]*8), (__builtin_popcount(PL.CregEps[0]&tid)&1)!=0);
    reg_gate<1>(a, load_gc(Utab+PL.CregGi[1]*8), (__builtin_popcount(PL.CregEps[1]&tid)&1)!=0);
    reg_gate<2>(a, load_gc(Utab+PL.CregGi[2]*8), (__builtin_popcount(PL.CregEps[2]&tid)&1)!=0);
    reg_gate<3>(a, load_gc(Utab+PL.CregGi[3]*8), (__builtin_popcount(PL.CregEps[3]&tid)&1)!=0);
    lane_gate<0,0u>(a, load_gc(Utab+PL.ClaneGi[0]*8),
        (((tid&1u)!=0) != ((__builtin_popcount(PL.ClaneEps[0]&tid)&1)!=0)), lane);
    lane_gate<1,0u>(a, load_gc(Utab+PL.ClaneGi[1]*8),
        (((tid&2u)!=0) != ((__builtin_popcount(PL.ClaneEps[1]&tid)&1)!=0)), lane);
    lane_gate<2,0u>(a, load_gc(Utab+PL.ClaneGi[2]*8),
        (((tid&4u)!=0) != ((__builtin_popcount(PL.ClaneEps[2]&tid)&1)!=0)), lane);
    lane_gate<3,0u>(a, load_gc(Utab+PL.ClaneGi[3]*8),
        (((tid&8u)!=0) != ((__builtin_popcount(PL.ClaneEps[3]&tid)&1)!=0)), lane);

    float acc[NQ];
#pragma unroll
    for(int w=0;w<NQ;++w) acc[w]=0.f;
#pragma unroll
    for(int j=0;j<16;++j){
      float p = a[j][0]*a[j][0] + a[j][1]*a[j][1];
#pragma unroll
      for(int w=0;w<NQ;++w){
        if(__builtin_popcount(PL.EJ4[w] & (unsigned)j) & 1) acc[w]-=p; else acc[w]+=p;
      }
    }
    const int wave = tid >> 6;
#pragma unroll
    for(int w=0;w<NQ;++w){
      float v = (__builtin_popcount(PL.ET[w]&tid)&1) ? -acc[w] : acc[w];
#pragma unroll
      for(int off=32; off>0; off>>=1) v += __shfl_down(v, off, 64);
      if(lane==0) red[wave][w]=v;
    }
    __syncthreads();
    if(tid < NQ){
      float s=0.f;
#pragma unroll
      for(int wv=0; wv<NWAVES; ++wv) s += red[wv][tid];
      out[b*NQ + tid] = s;
    }
  }
}

}  // namespace

extern "C" void kernel_launch(void* const* d_in, const int* in_sizes, int n_in,
                              void* d_out, int out_size, void* d_ws, size_t ws_size,
                              hipStream_t stream) {
  const float* x   = (const float*)d_in[0];   // (batch, 14) f32
  const float* prm = (const float*)d_in[1];   // (3, 14, 3) f32
  float* out = (float*)d_out;                 // (batch, 14) f32
  const int batch = in_sizes[0] / NQ;
  prep_gates<<<1, 64, 0, stream>>>(prm, (float*)d_ws);
  qsim_kernel<<<batch, BLOCK, 0, stream>>>(x, prm, (const float*)d_ws, out);
}

// Round 8
// 39.632 us; speedup vs baseline: 1.1018x; 1.1018x over previous
//
#include <hip/hip_runtime.h>

namespace {

using v2f = __attribute__((ext_vector_type(2))) float;

constexpr int NQ      = 14;
constexpr int NSTATES = 1 << NQ;
constexpr int BLOCK   = 1024;
constexpr int NWAVES  = BLOCK / 64;

// ---------------- compile-time GF(2) machinery ----------------
constexpr unsigned cparity(unsigned x){ x^=x>>8; x^=x>>4; x^=x>>2; x^=x>>1; return x&1u; }

struct Mat { unsigned row[NQ]; unsigned col[NQ]; };

constexpr Mat m_after(int nr){
  Mat m{};
  for(int p=0;p<NQ;++p){ m.row[p]=1u<<p; m.col[p]=1u<<p; }
  for(int l=0;l<nr;++l)
    for(int q=0;q<NQ;++q){
      int cq=(q==NQ-1)?NQ-1:q, tq=(q==NQ-1)?0:q+1;
      int Pc=NQ-1-cq, Pt=NQ-1-tq;
      m.row[Pt]^=m.row[Pc]; m.col[Pc]^=m.col[Pt];
    }
  return m;
}

constexpr Mat M1=m_after(1), M2=m_after(2), M3=m_after(3);
constexpr unsigned amask(int q){ return M1.col[NQ-1-q]; }
constexpr unsigned arow (int q){ return M1.row[NQ-1-q]; }
constexpr unsigned bmask(int q){ return M2.col[NQ-1-q]; }
constexpr unsigned brow (int q){ return M2.row[NQ-1-q]; }

constexpr int rank_of(const unsigned* v, int n){
  unsigned a[24]{};
  for(int i=0;i<n;++i) a[i]=v[i];
  int r=0;
  for(int bit=15;bit>=0;--bit){
    int p=-1;
    for(int i=r;i<n;++i){ if((a[i]>>bit)&1){ p=i; break; } }
    if(p<0) continue;
    unsigned t=a[r]; a[r]=a[p]; a[p]=t;
    for(int i=0;i<n;++i) if(i!=r && ((a[i]>>bit)&1)) a[i]^=a[r];
    ++r;
  }
  return r;
}

struct Plan {
  unsigned A[14], B[14], C[14];
  int BlaneGi[6]; unsigned BlanePi4[6];
  int BregGi[4];  unsigned BregEps[4];
  int CregGi[4];  unsigned CregEps[4];
  int ClaneGi[4]; unsigned ClaneEps[4];
  unsigned EJ4[14], ET[14];
};

constexpr Plan make_plan(){
  Plan P{};
  for(int t=0;t<14;++t) P.A[t]=amask(t);
  for(int t=0;t<4;++t){ P.B[t]=amask(10+t); P.BregGi[t]=10+t; }
  bool used[14]{}; int picked[14]{}; int np=0;
  {
    unsigned cur[20]{}; int nc=0;
    for(int t=0;t<4;++t) cur[nc++]=P.B[t];
    for(int q=0;q<14 && np<10;++q){
      cur[nc]=bmask(q);
      if(rank_of(cur,nc+1)==nc+1){ ++nc; picked[np++]=q; used[q]=true; }
    }
  }
  for(int i=0;i<6;++i){ P.B[4+i]=bmask(picked[i]); P.BlaneGi[i]=14+picked[i]; }
  int wq[4]{}, un[4]{}; int nu=0;
  for(int i=0;i<4;++i){ wq[i]=picked[6+i]; P.B[10+i]=bmask(wq[i]); P.CregGi[i]=14+wq[i]; }
  for(int q=0;q<14;++q) if(!used[q]) un[nu++]=q;
  for(int i=0;i<4;++i) P.ClaneGi[i]=14+un[i];
  for(int i=0;i<4;++i){ unsigned m=0;
    for(int t=0;t<10;++t) m |= cparity(arow(10+i)&P.B[4+t])<<t;
    P.BregEps[i]=m; }
  for(int i=0;i<6;++i){ unsigned m=0;
    for(int t=0;t<4;++t) m |= cparity(brow(picked[i])&P.B[t])<<t;
    P.BlanePi4[i]=m; }
  for(int t=0;t<4;++t) P.C[t]=bmask(wq[t]);
  for(int t=0;t<4;++t) P.C[4+t]=bmask(un[t]);
  {
    unsigned cc[20]{}; int n=0;
    for(int t=0;t<8;++t) cc[n++]=P.C[t];
    int pos=8;
    for(int p=0;p<14 && pos<14;++p){
      cc[n]=1u<<p;
      if(rank_of(cc,n+1)==n+1){ P.C[pos]=1u<<p; ++n; ++pos; }
    }
  }
  for(int i=0;i<4;++i){ unsigned m=0;
    for(int t=0;t<10;++t) m |= cparity(brow(wq[i])&P.C[4+t])<<t;
    P.CregEps[i]=m; }
  for(int i=0;i<4;++i){ unsigned m=0;
    for(int t=0;t<10;++t){ if(t==i) continue; m |= cparity(brow(un[i])&P.C[4+t])<<t; }
    P.ClaneEps[i]=m; }
  for(int w=0;w<14;++w){
    unsigned R=M3.row[NQ-1-w]; unsigned mj=0, mt=0;
    for(int t=0;t<4;++t)  mj |= cparity(R&P.C[t])<<t;
    for(int t=0;t<10;++t) mt |= cparity(R&P.C[4+t])<<t;
    P.EJ4[w]=mj; P.ET[w]=mt;
  }
  return P;
}

constexpr Plan PL = make_plan();
static_assert(rank_of(PL.A,14)==14, "phase A map not bijective");
static_assert(rank_of(PL.B,14)==14, "phase B map not bijective");
static_assert(rank_of(PL.C,14)==14, "phase C map not bijective");

// ---- basis inversion + phase transition matrices (all constexpr) ----
struct Inv { unsigned col[NQ]; };   // col[p] = coords of e_p in the basis
constexpr Inv inv_basis(const unsigned* bas){
  unsigned vec[NQ]{}, cmb[NQ]{}; bool used[NQ]{}; int pivk[NQ]{};
  for(int k=0;k<NQ;++k){ vec[k]=bas[k]; cmb[k]=1u<<k; }
  for(int b=0;b<NQ;++b){
    int p=-1;
    for(int k=0;k<NQ;++k) if(!used[k] && ((vec[k]>>b)&1)){ p=k; break; }
    used[p]=true; pivk[b]=p;
    for(int k=0;k<NQ;++k) if(k!=p && ((vec[k]>>b)&1)){ vec[k]^=vec[p]; cmb[k]^=cmb[p]; }
  }
  Inv R{};
  for(int b=0;b<NQ;++b) R.col[b]=cmb[pivk[b]];
  return R;
}
constexpr bool check_inv(const unsigned* bas, const Inv& iv){
  for(int p=0;p<NQ;++p){
    unsigned s=0;
    for(int k=0;k<NQ;++k) if((iv.col[p]>>k)&1) s^=bas[k];
    if(s != (1u<<p)) return false;
  }
  return true;
}
constexpr Inv IA = inv_basis(PL.A), IB = inv_basis(PL.B), IC = inv_basis(PL.C);
static_assert(check_inv(PL.A, IA), "IA");
static_assert(check_inv(PL.B, IB), "IB");
static_assert(check_inv(PL.C, IC), "IC");

struct Trans { unsigned t[NQ]; };   // t[k] = next-phase coords of current basis vec k
constexpr Trans trans_phys(const Inv& iv){
  Trans T{};
  for(int p=0;p<NQ;++p) T.t[p]=iv.col[p];
  return T;
}
constexpr Trans trans_of(const unsigned* cur, const Inv& iv){
  Trans T{};
  for(int k=0;k<NQ;++k){
    unsigned c=0;
    for(int p=0;p<NQ;++p) if((cur[k]>>p)&1) c^=iv.col[p];
    T.t[k]=c;
  }
  return T;
}
constexpr Trans T_PA = trans_phys(IA);
constexpr Trans T_AB = trans_of(PL.A, IB);
constexpr Trans T_BC = trans_of(PL.B, IC);

struct CJ { unsigned v[16]; };
constexpr CJ mk_cj(const Trans& T){
  CJ c{};
  for(int j=0;j<16;++j){
    unsigned s=0;
    for(int b=0;b<4;++b) if((j>>b)&1) s^=T.t[b];
    c.v[j]=s;
  }
  return c;
}
constexpr CJ CJ_PA=mk_cj(T_PA), CJ_AB=mk_cj(T_AB), CJ_BC=mk_cj(T_BC);

// ---------------- packed-f32 complex helpers ----------------
__device__ __forceinline__ v2f mkv(float a, float b){ v2f r; r[0]=a; r[1]=b; return r; }

__device__ __forceinline__ v2f pk_mul(v2f a, v2f b){
  v2f d; asm("v_pk_mul_f32 %0, %1, %2 op_sel:[0,0] op_sel_hi:[1,1]" : "=v"(d) : "v"(a), "v"(b)); return d;
}
__device__ __forceinline__ v2f pk_fma(v2f a, v2f b, v2f c){
  v2f d; asm("v_pk_fma_f32 %0, %1, %2, %3 op_sel:[0,0,0] op_sel_hi:[1,1,1]" : "=v"(d) : "v"(a), "v"(b), "v"(c)); return d;
}
__device__ __forceinline__ v2f pk_fma_swap1(v2f a, v2f b, v2f c){
  v2f d; asm("v_pk_fma_f32 %0, %1, %2, %3 op_sel:[0,1,0] op_sel_hi:[1,0,1]" : "=v"(d) : "v"(a), "v"(b), "v"(c)); return d;
}
__device__ __forceinline__ v2f cmul_pk(v2f uxx, v2f uyn, v2f s){ return pk_fma_swap1(uyn, s, pk_mul(uxx, s)); }
__device__ __forceinline__ v2f cfma_pk(v2f uxx, v2f uyn, v2f s, v2f acc){ return pk_fma_swap1(uyn, s, pk_fma(uxx, s, acc)); }

__device__ __forceinline__ float2 cmulf(float2 a, float2 b){
  return make_float2(a.x*b.x - a.y*b.y, a.x*b.y + a.y*b.x);
}
__device__ __forceinline__ v2f sel2(bool c, v2f x, v2f y){ v2f r; r[0]=c?x[0]:y[0]; r[1]=c?x[1]:y[1]; return r; }

struct GC { v2f u00x,u00n,u01x,u01n,u10x,u10n,u11x,u11n; };
__device__ __forceinline__ GC load_gc(const v2f* __restrict__ g){
  GC c{g[0],g[1],g[2],g[3],g[4],g[5],g[6],g[7]}; return c;
}

// ---- lane exchange (partner value) ----
template<int CTRL>
__device__ __forceinline__ int dpp(int x){
  return __builtin_amdgcn_update_dpp(0, x, CTRL, 0xF, 0xF, true);
}
// ^32 partner via permlane32_swap (verified R7)
__device__ __forceinline__ int x32(int x, unsigned lane){
  auto r = __builtin_amdgcn_permlane32_swap((unsigned)x, (unsigned)x, false, false);
  return (lane & 32u) ? (int)r[0] : (int)r[1];
}
// K: 0:^1 1:^2 2:^4 3:^8 4:^16 5:^32
template<int K>
__device__ __forceinline__ v2f xpart(v2f v, unsigned lane){
  int x0=__float_as_int(v[0]), x1=__float_as_int(v[1]);
  int y0, y1;
  if constexpr (K==0){ y0=dpp<0xB1>(x0);  y1=dpp<0xB1>(x1); }          // quad_perm ^1
  else if constexpr (K==1){ y0=dpp<0x4E>(x0);  y1=dpp<0x4E>(x1); }     // quad_perm ^2
  else if constexpr (K==2){                                            // ^4 (verified)
    y0=__builtin_amdgcn_ds_swizzle(x0,0x101F);
    y1=__builtin_amdgcn_ds_swizzle(x1,0x101F);
  }
  else if constexpr (K==3){ y0=dpp<0x128>(x0); y1=dpp<0x128>(x1); }    // row_ror:8 == ^8
  else if constexpr (K==4){                                            // ^16 (verified)
    y0=__builtin_amdgcn_ds_swizzle(x0,0x401F);
    y1=__builtin_amdgcn_ds_swizzle(x1,0x401F);
  }
  else { y0=x32(x0,lane); y1=x32(x1,lane); }                           // ^32 (verified)
  v2f r; r[0]=__int_as_float(y0); r[1]=__int_as_float(y1); return r;
}

template<int BIT>
__device__ __forceinline__ void reg_gate(v2f (&a)[16], const GC& c, bool eps){
  v2f m00x=sel2(eps,c.u11x,c.u00x), m00n=sel2(eps,c.u11n,c.u00n);
  v2f m01x=sel2(eps,c.u10x,c.u01x), m01n=sel2(eps,c.u10n,c.u01n);
  v2f m10x=sel2(eps,c.u01x,c.u10x), m10n=sel2(eps,c.u01n,c.u10n);
  v2f m11x=sel2(eps,c.u00x,c.u11x), m11n=sel2(eps,c.u00n,c.u11n);
#pragma unroll
  for(int v=0; v<16; ++v){
    if(!((v>>BIT)&1)){
      int w = v | (1<<BIT);
      v2f a0=a[v], a1=a[w];
      a[v] = cfma_pk(m01x,m01n,a1, cmul_pk(m00x,m00n,a0));
      a[w] = cfma_pk(m11x,m11n,a1, cmul_pk(m10x,m10n,a0));
    }
  }
}

// batched lane gate: 8 exchanges prefetched into th[] before use (deep pipelining)
template<int XK, unsigned PI4>
__device__ __forceinline__ void lane_gate(v2f (&a)[16], const GC& c, bool sel, unsigned lane){
  v2f kax0=sel2(sel,c.u11x,c.u00x), kan0=sel2(sel,c.u11n,c.u00n);
  v2f kbx0=sel2(sel,c.u10x,c.u01x), kbn0=sel2(sel,c.u10n,c.u01n);
  v2f kax1=sel2(sel,c.u00x,c.u11x), kan1=sel2(sel,c.u00n,c.u11n);
  v2f kbx1=sel2(sel,c.u01x,c.u10x), kbn1=sel2(sel,c.u01n,c.u10n);
#pragma unroll
  for(int h=0;h<2;++h){
    v2f th[8];
#pragma unroll
    for(int jj=0;jj<8;++jj) th[jj] = xpart<XK>(a[h*8+jj], lane);
#pragma unroll
    for(int jj=0;jj<8;++jj){
      const int j = h*8+jj;
      constexpr unsigned PP = PI4;   // compile-time
      bool pi = (__builtin_popcount(PP & (unsigned)j) & 1) != 0;  // folds per unrolled j
      v2f kax = pi?kax1:kax0, kan = pi?kan1:kan0;
      v2f kbx = pi?kbx1:kbx0, kbn = pi?kbn1:kbn0;
      a[j] = cfma_pk(kbx,kbn,th[jj], cmul_pk(kax,kan,a[j]));
    }
  }
}

__device__ __forceinline__ unsigned nb_of(unsigned tid, const unsigned (&t)[NQ]){
  unsigned s=0;
#pragma unroll
  for(int k=0;k<10;++k) s ^= t[4+k] & (0u-((tid>>k)&1u));
  return s;
}

__device__ __forceinline__ void scatter16(v2f* __restrict__ st, const v2f (&a)[16],
                                          unsigned nb, const CJ& cj){
#pragma unroll
  for(int j=0;j<16;++j){
    unsigned d = nb ^ cj.v[j];
    st[d + (d>>4)] = a[j];
  }
}

// ---------------- kernel ----------------
__global__ __launch_bounds__(BLOCK, 4) void qsim_kernel(
    const float* __restrict__ x,
    const float* __restrict__ prm,
    float* __restrict__ out)
{
  __shared__ v2f    st[BLOCK*17];     // phase-ordered state, 8B pad per thread (136 KiB)
  __shared__ v2f    Utab[28*8];       // gate constants (layers 1,2)
  __shared__ float2 l0c[NQ][2];
  __shared__ float  red[NWAVES][NQ];

  const int b = blockIdx.x;
  const unsigned tid = threadIdx.x;
  const unsigned lane = tid & 63u;

  // ---- gate table built in-kernel (28 threads; was prep_gates) ----
  if(tid < 28){
    int t = tid;
    int l = 1 + t/NQ, q = t % NQ;
    float ax=prm[(l*NQ+q)*3+0], ay=prm[(l*NQ+q)*3+1], az=prm[(l*NQ+q)*3+2];
    float cx,sx,cy,sy,cz,sz;
    sincosf(0.5f*ax,&sx,&cx); sincosf(0.5f*ay,&sy,&cy); sincosf(0.5f*az,&sz,&cz);
    float2 M00=make_float2(cy*cx, sy*sx),  M01=make_float2(-sy*cx,-cy*sx);
    float2 M10=make_float2(sy*cx,-cy*sx),  M11=make_float2(cy*cx,-sy*sx);
    float2 ez =make_float2(cz,-sz), ezc=make_float2(cz,sz);
    float2 U00=cmulf(ez,M00), U01=cmulf(ez,M01), U10=cmulf(ezc,M10), U11=cmulf(ezc,M11);
    v2f* U = &Utab[t*8];
    U[0]=mkv(U00.x,U00.x); U[1]=mkv(-U00.y,U00.y);
    U[2]=mkv(U01.x,U01.x); U[3]=mkv(-U01.y,U01.y);
    U[4]=mkv(U10.x,U10.x); U[5]=mkv(-U10.y,U10.y);
    U[6]=mkv(U11.x,U11.x); U[7]=mkv(-U11.y,U11.y);
  }
  // ---- layer-0 columns (x-dependent) ----
  if(tid < NQ){
    int q = tid;
    float ax = prm[q*3+0] + x[b*NQ+q];
    float ay = prm[q*3+1], az = prm[q*3+2];
    float cx,sx,cy,sy,cz,sz;
    sincosf(0.5f*ax,&sx,&cx); sincosf(0.5f*ay,&sy,&cy); sincosf(0.5f*az,&sz,&cz);
    l0c[q][0] = cmulf(make_float2(cz,-sz), make_float2(cy*cx,  sy*sx));   // U00
    l0c[q][1] = cmulf(make_float2(cz, sz), make_float2(sy*cx, -cy*sx));   // U10
  }
  __syncthreads();

  // ---- init: product state for s = (tid<<4)|j, scattered into phase-A layout ----
  {
    float2 Pk = l0c[0][(tid>>9)&1];
#pragma unroll
    for(int q=1;q<10;++q) Pk = cmulf(Pk, l0c[q][(tid>>(9-q))&1]);
    float2 t2[2], t4[4];
    t2[0]=cmulf(Pk,l0c[10][0]); t2[1]=cmulf(Pk,l0c[10][1]);
#pragma unroll
    for(int i=0;i<2;++i){ t4[2*i]=cmulf(t2[i],l0c[11][0]); t4[2*i+1]=cmulf(t2[i],l0c[11][1]); }
    v2f a[16];
#pragma unroll
    for(int j=0;j<16;++j){
      float2 v = cmulf(cmulf(t4[j>>2], l0c[12][(j>>1)&1]), l0c[13][j&1]);
      a[j] = mkv(v.x, v.y);
    }
    scatter16(st, a, nb_of(tid, T_PA.t), CJ_PA);
  }
  __syncthreads();

  // ---- phase A: 4 reg + 6 lane layer-1 gates ----
  {
    v2f a[16];
    const int rb = (int)tid*17;
#pragma unroll
    for(int j=0;j<16;++j) a[j] = st[rb + j];
    reg_gate<0>(a, load_gc(Utab+0*8), false);
    reg_gate<1>(a, load_gc(Utab+1*8), false);
    reg_gate<2>(a, load_gc(Utab+2*8), false);
    reg_gate<3>(a, load_gc(Utab+3*8), false);
    lane_gate<0,0u>(a, load_gc(Utab+4*8), (tid&1)!=0,  lane);
    lane_gate<1,0u>(a, load_gc(Utab+5*8), (tid&2)!=0,  lane);
    lane_gate<2,0u>(a, load_gc(Utab+6*8), (tid&4)!=0,  lane);
    lane_gate<3,0u>(a, load_gc(Utab+7*8), (tid&8)!=0,  lane);
    lane_gate<4,0u>(a, load_gc(Utab+8*8), (tid&16)!=0, lane);
    lane_gate<5,0u>(a, load_gc(Utab+9*8), (tid&32)!=0, lane);
    __syncthreads();                      // all reads done before cross-layout writes
    scatter16(st, a, nb_of(tid, T_AB.t), CJ_AB);
  }
  __syncthreads();

  // ---- phase B: 4 leftover layer-1 reg gates (runtime eps) + 6 layer-2 lane gates ----
  {
    v2f a[16];
    const int rb = (int)tid*17;
#pragma unroll
    for(int j=0;j<16;++j) a[j] = st[rb + j];
    reg_gate<0>(a, load_gc(Utab+PL.BregGi[0]*8), (__builtin_popcount(PL.BregEps[0]&tid)&1)!=0);
    reg_gate<1>(a, load_gc(Utab+PL.BregGi[1]*8), (__builtin_popcount(PL.BregEps[1]&tid)&1)!=0);
    reg_gate<2>(a, load_gc(Utab+PL.BregGi[2]*8), (__builtin_popcount(PL.BregEps[2]&tid)&1)!=0);
    reg_gate<3>(a, load_gc(Utab+PL.BregGi[3]*8), (__builtin_popcount(PL.BregEps[3]&tid)&1)!=0);
    lane_gate<0,PL.BlanePi4[0]>(a, load_gc(Utab+PL.BlaneGi[0]*8), (tid&1)!=0,  lane);
    lane_gate<1,PL.BlanePi4[1]>(a, load_gc(Utab+PL.BlaneGi[1]*8), (tid&2)!=0,  lane);
    lane_gate<2,PL.BlanePi4[2]>(a, load_gc(Utab+PL.BlaneGi[2]*8), (tid&4)!=0,  lane);
    lane_gate<3,PL.BlanePi4[3]>(a, load_gc(Utab+PL.BlaneGi[3]*8), (tid&8)!=0,  lane);
    lane_gate<4,PL.BlanePi4[4]>(a, load_gc(Utab+PL.BlaneGi[4]*8), (tid&16)!=0, lane);
    lane_gate<5,PL.BlanePi4[5]>(a, load_gc(Utab+PL.BlaneGi[5]*8), (tid&32)!=0, lane);
    __syncthreads();
    scatter16(st, a, nb_of(tid, T_BC.t), CJ_BC);
  }
  __syncthreads();

  // ---- phase C: last 8 layer-2 gates, expectation from registers ----
  {
    v2f a[16];
    const int rb = (int)tid*17;
#pragma unroll
    for(int j=0;j<16;++j) a[j] = st[rb + j];
    reg_gate<0>(a, load_gc(Utab+PL.CregGi[0]*8), (__builtin_popcount(PL.CregEps[0]&tid)&1)!=0);
    reg_gate<1>(a, load_gc(Utab+PL.CregGi[1]*8), (__builtin_popcount(PL.CregEps[1]&tid)&1)!=0);
    reg_gate<2>(a, load_gc(Utab+PL.CregGi[2]*8), (__builtin_popcount(PL.CregEps[2]&tid)&1)!=0);
    reg_gate<3>(a, load_gc(Utab+PL.CregGi[3]*8), (__builtin_popcount(PL.CregEps[3]&tid)&1)!=0);
    lane_gate<0,0u>(a, load_gc(Utab+PL.ClaneGi[0]*8),
        (((tid&1u)!=0) != ((__builtin_popcount(PL.ClaneEps[0]&tid)&1)!=0)), lane);
    lane_gate<1,0u>(a, load_gc(Utab+PL.ClaneGi[1]*8),
        (((tid&2u)!=0) != ((__builtin_popcount(PL.ClaneEps[1]&tid)&1)!=0)), lane);
    lane_gate<2,0u>(a, load_gc(Utab+PL.ClaneGi[2]*8),
        (((tid&4u)!=0) != ((__builtin_popcount(PL.ClaneEps[2]&tid)&1)!=0)), lane);
    lane_gate<3,0u>(a, load_gc(Utab+PL.ClaneGi[3]*8),
        (((tid&8u)!=0) != ((__builtin_popcount(PL.ClaneEps[3]&tid)&1)!=0)), lane);

    float acc[NQ];
#pragma unroll
    for(int w=0;w<NQ;++w) acc[w]=0.f;
#pragma unroll
    for(int j=0;j<16;++j){
      float p = a[j][0]*a[j][0] + a[j][1]*a[j][1];
#pragma unroll
      for(int w=0;w<NQ;++w){
        if(__builtin_popcount(PL.EJ4[w] & (unsigned)j) & 1) acc[w]-=p; else acc[w]+=p;
      }
    }
    const int wave = tid >> 6;
#pragma unroll
    for(int w=0;w<NQ;++w){
      float v = (__builtin_popcount(PL.ET[w]&tid)&1) ? -acc[w] : acc[w];
#pragma unroll
      for(int off=32; off>0; off>>=1) v += __shfl_down(v, off, 64);
      if(lane==0) red[wave][w]=v;
    }
    __syncthreads();
    if(tid < NQ){
      float s=0.f;
#pragma unroll
      for(int wv=0; wv<NWAVES; ++wv) s += red[wv][tid];
      out[b*NQ + tid] = s;
    }
  }
}

}  // namespace

extern "C" void kernel_launch(void* const* d_in, const int* in_sizes, int n_in,
                              void* d_out, int out_size, void* d_ws, size_t ws_size,
                              hipStream_t stream) {
  const float* x   = (const float*)d_in[0];   // (batch, 14) f32
  const float* prm = (const float*)d_in[1];   // (3, 14, 3) f32
  float* out = (float*)d_out;                 // (batch, 14) f32
  const int batch = in_sizes[0] / NQ;
  qsim_kernel<<<batch, BLOCK, 0, stream>>>(x, prm, out);
}